// Round 10
// baseline (1189.863 us; speedup 1.0000x reference)
//
#include <hip/hip_runtime.h>
#include <cstdint>
#include <cstddef>

#define GLOBAL_AS __attribute__((address_space(1)))
#define LDS_AS    __attribute__((address_space(3)))

typedef __bf16 bf16;
typedef __bf16 bf16x4 __attribute__((ext_vector_type(4)));
typedef __bf16 bf16x8 __attribute__((ext_vector_type(8)));
typedef float  f32x4  __attribute__((ext_vector_type(4)));
typedef int    i32x4  __attribute__((ext_vector_type(4)));
typedef unsigned int u32x2 __attribute__((ext_vector_type(2)));

__device__ __forceinline__ void gl_lds16(const void* g, void* l) {
  // 16B-per-lane async global->LDS; LDS dest = wave-uniform base + lane*16
  __builtin_amdgcn_global_load_lds((GLOBAL_AS void*)g, (LDS_AS void*)l, 16, 0, 0);
}

// ---------------- LayerNorm: fp32 (rows of 2048) -> bf16 ----------------
__global__ __launch_bounds__(256) void ln_kernel(const float* __restrict__ x,
                                                 const float* __restrict__ w,
                                                 const float* __restrict__ bias,
                                                 bf16* __restrict__ out) {
  const int row = blockIdx.x;
  const int tid = threadIdx.x;
  const float* xr = x + (size_t)row * 2048;
  f32x4 v0 = ((const f32x4*)xr)[tid * 2];
  f32x4 v1 = ((const f32x4*)xr)[tid * 2 + 1];
  float s = 0.f, ss = 0.f;
#pragma unroll
  for (int j = 0; j < 4; ++j) { s += v0[j]; ss += v0[j] * v0[j]; }
#pragma unroll
  for (int j = 0; j < 4; ++j) { s += v1[j]; ss += v1[j] * v1[j]; }
#pragma unroll
  for (int d = 1; d < 64; d <<= 1) { s += __shfl_xor(s, d); ss += __shfl_xor(ss, d); }
  __shared__ float red[8];
  const int wave = tid >> 6, lane = tid & 63;
  if (lane == 0) { red[wave * 2] = s; red[wave * 2 + 1] = ss; }
  __syncthreads();
  s  = red[0] + red[2] + red[4] + red[6];
  ss = red[1] + red[3] + red[5] + red[7];
  const float mean = s * (1.f / 2048.f);
  const float var  = ss * (1.f / 2048.f) - mean * mean;  // biased, matches jnp var
  const float rstd = rsqrtf(var + 1e-5f);
  const int col = tid * 8;
  bf16x8 o;
#pragma unroll
  for (int j = 0; j < 4; ++j) o[j]     = (bf16)((v0[j] - mean) * rstd * w[col + j]     + bias[col + j]);
#pragma unroll
  for (int j = 0; j < 4; ++j) o[4 + j] = (bf16)((v1[j] - mean) * rstd * w[col + 4 + j] + bias[col + 4 + j]);
  *(bf16x8*)(out + (size_t)row * 2048 + col) = o;
}

// ---------------- LayerNorm + int8 row-quantize (for i8 GEMM path) ----------------
__global__ __launch_bounds__(256) void ln_q_kernel(const float* __restrict__ x,
    const float* __restrict__ w, const float* __restrict__ bias,
    char* __restrict__ qh, float* __restrict__ s_m, float* __restrict__ rs,
    float* __restrict__ de) {
  const int row = blockIdx.x;
  const int tid = threadIdx.x;
  const float* xr = x + (size_t)row * 2048;
  f32x4 v0 = ((const f32x4*)xr)[tid * 2];
  f32x4 v1 = ((const f32x4*)xr)[tid * 2 + 1];
  float s = 0.f, ss = 0.f;
#pragma unroll
  for (int j = 0; j < 4; ++j) { s += v0[j]; ss += v0[j] * v0[j]; }
#pragma unroll
  for (int j = 0; j < 4; ++j) { s += v1[j]; ss += v1[j] * v1[j]; }
#pragma unroll
  for (int d = 1; d < 64; d <<= 1) { s += __shfl_xor(s, d); ss += __shfl_xor(ss, d); }
  __shared__ float red[12];
  const int wave = tid >> 6, lane = tid & 63;
  if (lane == 0) { red[wave * 2] = s; red[wave * 2 + 1] = ss; }
  __syncthreads();
  s  = red[0] + red[2] + red[4] + red[6];
  ss = red[1] + red[3] + red[5] + red[7];
  const float mean = s * (1.f / 2048.f);
  const float var  = ss * (1.f / 2048.f) - mean * mean;
  const float rstd = rsqrtf(var + 1e-5f);
  const int col = tid * 8;
  float y[8];
#pragma unroll
  for (int j = 0; j < 4; ++j) y[j]     = (v0[j] - mean) * rstd * w[col + j]     + bias[col + j];
#pragma unroll
  for (int j = 0; j < 4; ++j) y[4 + j] = (v1[j] - mean) * rstd * w[col + 4 + j] + bias[col + 4 + j];
  float sy = 0.f, mx = 0.f;
#pragma unroll
  for (int j = 0; j < 8; ++j) { sy += y[j]; mx = fmaxf(mx, fabsf(y[j])); }
#pragma unroll
  for (int d = 1; d < 64; d <<= 1) { sy += __shfl_xor(sy, d); mx = fmaxf(mx, __shfl_xor(mx, d)); }
  __syncthreads();  // red reuse
  if (lane == 0) { red[wave * 2] = sy; red[wave * 2 + 1] = mx; }
  __syncthreads();
  const float sya = red[0] + red[2] + red[4] + red[6];
  const float mxa = fmaxf(fmaxf(red[1], red[3]), fmaxf(red[5], red[7]));
  const float inv = 127.f / fmaxf(mxa, 1e-8f);
  unsigned int lo = 0, hi = 0;
  int qs = 0;
#pragma unroll
  for (int j = 0; j < 4; ++j) { int qi = (int)rintf(y[j] * inv);     qs += qi; lo |= ((unsigned int)qi & 0xffu) << (8 * j); }
#pragma unroll
  for (int j = 0; j < 4; ++j) { int qi = (int)rintf(y[4 + j] * inv); qs += qi; hi |= ((unsigned int)qi & 0xffu) << (8 * j); }
  u32x2 st; st[0] = lo; st[1] = hi;
  *(u32x2*)(qh + (size_t)row * 2048 + col) = st;
  float fqs = (float)qs;
#pragma unroll
  for (int d = 1; d < 64; d <<= 1) fqs += __shfl_xor(fqs, d);
  __syncthreads();
  if (lane == 0) red[8 + wave] = fqs;
  __syncthreads();
  if (tid == 0) {
    const float qsa = red[8] + red[9] + red[10] + red[11];
    const float smv = fmaxf(mxa, 1e-8f) / 127.f;
    s_m[row] = smv; rs[row] = sya; de[row] = sya - smv * qsa;
  }
}

// -------- Dequant + LoRA fold: W[o,i] = qw*sc[o]+zp[o]+2*(B@A)[o,i] --------
__device__ __forceinline__ void dequant_body(const int* qw, const float* sc,
    const float* zp, const float* A, const float* Bm, bf16* W, int in_f,
    int bid, int tid) {
  const int per_row = in_f >> 3;
  const int idx = bid * 256 + tid;
  const int o  = idx / per_row;
  const int i0 = (idx - o * per_row) << 3;
  const float s = sc[o], z = zp[o];
  float bl[16];
#pragma unroll
  for (int r = 0; r < 16; ++r) bl[r] = Bm[o * 16 + r];
  float acc[8] = {0.f, 0.f, 0.f, 0.f, 0.f, 0.f, 0.f, 0.f};
#pragma unroll
  for (int r = 0; r < 16; ++r) {
    const f32x4* ap = (const f32x4*)(A + (size_t)r * in_f + i0);
    f32x4 a0 = ap[0], a1 = ap[1];
#pragma unroll
    for (int j = 0; j < 4; ++j) { acc[j] += bl[r] * a0[j]; acc[4 + j] += bl[r] * a1[j]; }
  }
  const int* qp = qw + (size_t)o * in_f + i0;
  bf16x8 w8;
#pragma unroll
  for (int j = 0; j < 8; ++j) w8[j] = (bf16)((float)qp[j] * s + z + 2.f * acc[j]);
  *(bf16x8*)(W + (size_t)o * in_f + i0) = w8;
}

__global__ __launch_bounds__(256) void dequant_kernel(const int* __restrict__ qw,
    const float* __restrict__ sc, const float* __restrict__ zp,
    const float* __restrict__ A, const float* __restrict__ Bm,
    bf16* __restrict__ W, int out_f, int in_f) {
  dequant_body(qw, sc, zp, A, Bm, W, in_f, blockIdx.x, threadIdx.x);
}

// merged q|k|v dequant: 6144 blocks, segment = blockIdx>>11
__global__ __launch_bounds__(256) void dequant3_kernel(
    const int* q_qw, const float* q_sc, const float* q_zp, const float* q_A, const float* q_B,
    const int* k_qw, const float* k_sc, const float* k_zp, const float* k_A, const float* k_B,
    const int* v_qw, const float* v_sc, const float* v_zp, const float* v_A, const float* v_B,
    bf16* W) {
  const int seg = blockIdx.x >> 11;
  const int bid = blockIdx.x & 2047;
  const int* qw = (seg == 0) ? q_qw : (seg == 1) ? k_qw : v_qw;
  const float* sc = (seg == 0) ? q_sc : (seg == 1) ? k_sc : v_sc;
  const float* zp = (seg == 0) ? q_zp : (seg == 1) ? k_zp : v_zp;
  const float* A  = (seg == 0) ? q_A  : (seg == 1) ? k_A  : v_A;
  const float* Bm = (seg == 0) ? q_B  : (seg == 1) ? k_B  : v_B;
  dequant_body(qw, sc, zp, A, Bm, W + (size_t)seg * 2048 * 2048, 2048, bid, threadIdx.x);
}

// -------- int32 -> int8 weight pack + per-row mean weight (one 2048-row per block) --------
__global__ __launch_bounds__(256) void pack_w_kernel(const int* __restrict__ qw,
    const float* __restrict__ sc, char* __restrict__ out, float* __restrict__ wsum) {
  const int row = blockIdx.x;
  const int tid = threadIdx.x;
  const size_t idx = (size_t)row * 2048 + tid * 8;
  i32x4 a = *(const i32x4*)(qw + idx);
  i32x4 b = *(const i32x4*)(qw + idx + 4);
  unsigned int lo = ((unsigned)a[0] & 0xffu) | (((unsigned)a[1] & 0xffu) << 8) |
                    (((unsigned)a[2] & 0xffu) << 16) | (((unsigned)a[3] & 0xffu) << 24);
  unsigned int hi = ((unsigned)b[0] & 0xffu) | (((unsigned)b[1] & 0xffu) << 8) |
                    (((unsigned)b[2] & 0xffu) << 16) | (((unsigned)b[3] & 0xffu) << 24);
  u32x2 st; st[0] = lo; st[1] = hi;
  *(u32x2*)(out + idx) = st;
  float fs = (float)(a[0] + a[1] + a[2] + a[3] + b[0] + b[1] + b[2] + b[3]);
#pragma unroll
  for (int d = 1; d < 64; d <<= 1) fs += __shfl_xor(fs, d);
  __shared__ float red[4];
  const int wave = tid >> 6, lane = tid & 63;
  if (lane == 0) red[wave] = fs;
  __syncthreads();
  if (tid == 0) wsum[row] = sc[row] * (red[0] + red[1] + red[2] + red[3]) * (1.f / 2048.f);
}

// -------- LoRA B matrices -> bf16 [N][32], x2 scale, zero-padded per matrix --------
__global__ __launch_bounds__(256) void pack_b2_kernel(const float* __restrict__ gB,
    const float* __restrict__ uB, bf16* __restrict__ B2g, bf16* __restrict__ B2u) {
  const int idx = blockIdx.x * 256 + threadIdx.x;   // 8192*32
  const int nn = idx >> 5, r = idx & 31;
  B2g[idx] = (r < 16)  ? (bf16)(2.f * gB[nn * 16 + r])        : (bf16)0.f;
  B2u[idx] = (r >= 16) ? (bf16)(2.f * uB[nn * 16 + (r - 16)]) : (bf16)0.f;
}

// -------- hA[m][0..32) = s_m * (qh @ [Ag|Au].T), bf16 --------
__global__ __launch_bounds__(256) void hA_kernel(const char* __restrict__ qh,
    const float* __restrict__ s_m, const float* __restrict__ Ag,
    const float* __restrict__ Au, bf16* __restrict__ hA) {
  __shared__ bf16 Asm[32 * 512];
  const int tid = threadIdx.x, wave = tid >> 6, lane = tid & 63;
  const int row = blockIdx.x * 4 + wave;
  float acc[32];
#pragma unroll
  for (int r = 0; r < 32; ++r) acc[r] = 0.f;
  for (int kb = 0; kb < 2048; kb += 512) {
    const int r2 = tid >> 3, c0 = (tid & 7) * 64;
    const float* src = (r2 < 16 ? Ag + (size_t)r2 * 2048 : Au + (size_t)(r2 - 16) * 2048) + kb + c0;
#pragma unroll
    for (int j = 0; j < 64; j += 8) {
      f32x4 va = *(const f32x4*)(src + j);
      f32x4 vb = *(const f32x4*)(src + j + 4);
      bf16x8 bv;
#pragma unroll
      for (int jj = 0; jj < 4; ++jj) { bv[jj] = (bf16)va[jj]; bv[4 + jj] = (bf16)vb[jj]; }
      *(bf16x8*)(Asm + r2 * 512 + c0 + j) = bv;
    }
    __syncthreads();
    float q[8];
    const char* qp = qh + (size_t)row * 2048 + kb + lane * 8;
#pragma unroll
    for (int j = 0; j < 8; ++j) q[j] = (float)qp[j];
#pragma unroll
    for (int r = 0; r < 32; ++r) {
      bf16x8 a8 = *(const bf16x8*)(Asm + r * 512 + lane * 8);
      float d = 0.f;
#pragma unroll
      for (int j = 0; j < 8; ++j) d += q[j] * (float)a8[j];
      acc[r] += d;
    }
    __syncthreads();
  }
  const float s = s_m[row];
#pragma unroll
  for (int r = 0; r < 32; ++r) {
    float v = acc[r];
#pragma unroll
    for (int d = 1; d < 64; d <<= 1) v += __shfl_xor(v, d);
    if (lane == 0) hA[(size_t)row * 32 + r] = (bf16)(s * v);
  }
}

// -------- bf16 GEMM, pipelined (round-2 validated form): C = A @ B^T --------
// 256x128 tile, BK=64, 8 waves (4M x 2N, per-wave 64x64), triple-buffered LDS,
// counted s_waitcnt vmcnt(6), setprio around MFMA, XCD-chunked block swizzle.
// 2 phases per K-tile (ks-half split), each: {8 ds_read_b128 + 3 stage loads ->
// barrier -> setprio -> 16 MFMA -> setprio -> barrier}.  MFMA:barrier = 8.
// VALIDATED: R1 (ratio 4) = 189.8us, R2 (this, ratio 8) = 158.9us, R3
// (1 barrier/K-tile) = 188.8us -> barrier alternation of the 2 waves/SIMD is
// load-bearing.  Structural ceiling for 64x64/wave ~= 42% MfmaUtil (LDS port
// and MFMA serialize across the barrier); measured 38%.
#define STAGE_A(t, buf, r8) gl_lds16(Ag + (size_t)(r8) * 8 * K + (size_t)(t) * 64, \
                                     &As[buf][((wave * 32) + (r8) * 8) * 64])
#define STAGE_B(t, buf, r8) gl_lds16(Bg + (size_t)(r8) * 8 * K + (size_t)(t) * 64, \
                                     &Bs[buf][((wave * 16) + (r8) * 8) * 64])

template <int MODE>
__global__ __launch_bounds__(512, 2) void gemm8_kernel(const bf16* __restrict__ A,
    const bf16* __restrict__ B, bf16* __restrict__ Cb, float* __restrict__ Cf,
    const float* __restrict__ res, bf16* __restrict__ vt,
    int M, int N, int K, int ldc) {
  const int tid = threadIdx.x;
  const int wave = tid >> 6, lane = tid & 63;
  const int lcol = lane & 15, lrow = lane >> 4;
  const int wm = (wave >> 1) * 64, wn = (wave & 1) * 64;
  // XCD-aware swizzle (all grids here are multiples of 8 blocks)
  const int nwg = gridDim.x * gridDim.y;
  const int bid = blockIdx.y * gridDim.x + blockIdx.x;
  const int swb = (bid & 7) * (nwg >> 3) + (bid >> 3);
  const int n0 = (swb % gridDim.x) * 128;
  const int m0 = (swb / gridDim.x) * 256;
  __shared__ bf16 As[3][256 * 64];   // 96 KiB
  __shared__ bf16 Bs[3][128 * 64];   // 48 KiB
  f32x4 acc[4][4] = {};
  const int sw = ((lane & 7) ^ ((lane >> 3) & 7)) * 8;
  const bf16* Ag = A + (size_t)(m0 + wave * 32 + (lane >> 3)) * K + sw;
  const bf16* Bg = B + (size_t)(n0 + wave * 16 + (lane >> 3)) * K + sw;
  const int nt = K >> 6;

  // prologue: stage tiles 0 and 1 (6 loads per wave per tile, FIFO order)
#pragma unroll
  for (int r8 = 0; r8 < 4; ++r8) STAGE_A(0, 0, r8);
  STAGE_B(0, 0, 0); STAGE_B(0, 0, 1);
#pragma unroll
  for (int r8 = 0; r8 < 4; ++r8) STAGE_A(1, 1, r8);
  STAGE_B(1, 1, 0); STAGE_B(1, 1, 1);
  asm volatile("s_waitcnt vmcnt(6)" ::: "memory");   // tile 0 resident
  __builtin_amdgcn_s_barrier();

  int cur = 0;
  for (int t = 0; t < nt; ++t) {
    const bf16* Ac = As[cur];
    const bf16* Bc = Bs[cur];
    const int nx = (cur >= 1) ? cur - 1 : 2;   // (cur+2)%3
    const bool pf = (t + 2 < nt);

    // ---- phase A: ks=0 fragments; stage first half of tile t+2
    bf16x8 a0[4], b0[4];
#pragma unroll
    for (int j = 0; j < 4; ++j)
      b0[j] = *(const bf16x8*)(Bc + (wn + j * 16 + lcol) * 64 + (lrow ^ (lcol & 7)) * 8);
#pragma unroll
    for (int i = 0; i < 4; ++i)
      a0[i] = *(const bf16x8*)(Ac + (wm + i * 16 + lcol) * 64 + (lrow ^ (lcol & 7)) * 8);
    if (pf) { STAGE_A(t + 2, nx, 0); STAGE_A(t + 2, nx, 1); STAGE_B(t + 2, nx, 0); }
    __builtin_amdgcn_s_barrier();
    __builtin_amdgcn_s_setprio(1);
#pragma unroll
    for (int i = 0; i < 4; ++i)
#pragma unroll
      for (int j = 0; j < 4; ++j)
        acc[i][j] = __builtin_amdgcn_mfma_f32_16x16x32_bf16(a0[i], b0[j], acc[i][j], 0, 0, 0);
    __builtin_amdgcn_s_setprio(0);
    __builtin_amdgcn_s_barrier();

    // ---- phase B: ks=1 fragments; stage second half of tile t+2; counted vmcnt
    bf16x8 a1[4], b1[4];
#pragma unroll
    for (int j = 0; j < 4; ++j)
      b1[j] = *(const bf16x8*)(Bc + (wn + j * 16 + lcol) * 64 + ((4 + lrow) ^ (lcol & 7)) * 8);
#pragma unroll
    for (int i = 0; i < 4; ++i)
      a1[i] = *(const bf16x8*)(Ac + (wm + i * 16 + lcol) * 64 + ((4 + lrow) ^ (lcol & 7)) * 8);
    if (pf) { STAGE_A(t + 2, nx, 2); STAGE_A(t + 2, nx, 3); STAGE_B(t + 2, nx, 1); }
    __builtin_amdgcn_s_barrier();
    __builtin_amdgcn_s_setprio(1);
#pragma unroll
    for (int i = 0; i < 4; ++i)
#pragma unroll
      for (int j = 0; j < 4; ++j)
        acc[i][j] = __builtin_amdgcn_mfma_f32_16x16x32_bf16(a1[i], b1[j], acc[i][j], 0, 0, 0);
    __builtin_amdgcn_s_setprio(0);
    // wait for tile t+1 only; leave t+2's 6 loads in flight (never drain to 0
    // in steady state)
    if (pf) asm volatile("s_waitcnt vmcnt(6)" ::: "memory");
    else    asm volatile("s_waitcnt vmcnt(0)" ::: "memory");
    __builtin_amdgcn_s_barrier();
    cur = (cur == 2) ? 0 : cur + 1;
  }

  // epilogue (same per-frag mapping as the verified 128^2 kernel)
#pragma unroll
  for (int i = 0; i < 4; ++i)
#pragma unroll
    for (int j = 0; j < 4; ++j) {
      const int row0 = m0 + wm + i * 16 + lrow * 4;
      const int col  = n0 + wn + j * 16 + lcol;
      if (MODE == 3 && col >= 4096) {
        const int c2 = col - 4096;
        bf16x4 v4;
#pragma unroll
        for (int r = 0; r < 4; ++r) v4[r] = (bf16)acc[i][j][r];
        *(bf16x4*)(vt + (size_t)(((row0 >> 11) * 16 + (c2 >> 7)) * 128 + (c2 & 127)) * 2048
                      + (row0 & 2047)) = v4;
      } else {
#pragma unroll
        for (int r = 0; r < 4; ++r) {
          const int row = row0 + r;
          const float v = acc[i][j][r];
          const size_t idx = (size_t)row * ldc + col;
          if (MODE == 1) Cf[idx] = res[idx] + v;
          else           Cb[idx] = (bf16)v;
        }
      }
    }
}
#undef STAGE_A
#undef STAGE_B

// -------- int8 GEMM, pipelined (same structure as bf16 winner): --------
// 256x128 tile, BK=128 bytes, 8 waves 4M x 2N, triple-buffered LDS (144 KiB),
// counted vmcnt(6), 2 phases/K-tile with 16 mfma_i32_16x16x64_i8 each.
// Epilogue: out[m,o] = sc[o]*s_m[m]*(qh@qw^T) + zp[o]*rs[m] + wsum[o]*de[m]
//           + (hA@B2^T).  MODE 0: bf16 store.  MODE 1: silu(gate)*val.
#define STAGE_A8(t, buf, r8) gl_lds16(Ag + (size_t)(r8) * 8 * K + (size_t)(t) * 128, \
                                      &As[buf][((wave * 32) + (r8) * 8) * 128])
#define STAGE_B8(t, buf, r8) gl_lds16(Bg + (size_t)(r8) * 8 * K + (size_t)(t) * 128, \
                                      &Bs[buf][((wave * 16) + (r8) * 8) * 128])

template <int MODE>
__global__ __launch_bounds__(512, 2) void gemm_i8_kernel(const char* __restrict__ Aq,
    const char* __restrict__ Bq, const float* __restrict__ s_m, const float* __restrict__ rs,
    const float* __restrict__ de, const float* __restrict__ sc, const float* __restrict__ zp,
    const float* __restrict__ wsum, const bf16* __restrict__ hA, const bf16* __restrict__ B2,
    bf16* __restrict__ Cb, const bf16* __restrict__ gate, int M, int N, int K) {
  const int tid = threadIdx.x;
  const int wave = tid >> 6, lane = tid & 63;
  const int lcol = lane & 15, lrow = lane >> 4;
  const int wm = (wave >> 1) * 64, wn = (wave & 1) * 64;
  // XCD-aware swizzle (grid 64x16 = 1024 blocks, %8==0)
  const int nwg = gridDim.x * gridDim.y;
  const int bid = blockIdx.y * gridDim.x + blockIdx.x;
  const int swb = (bid & 7) * (nwg >> 3) + (bid >> 3);
  const int n0 = (swb % gridDim.x) * 128;
  const int m0 = (swb / gridDim.x) * 256;
  __shared__ char As[3][256 * 128];   // 96 KiB
  __shared__ char Bs[3][128 * 128];   // 48 KiB
  i32x4 acc[4][4] = {};
  const int sw = ((lane & 7) ^ ((lane >> 3) & 7)) * 16;   // byte swizzle, 16B chunks
  const char* Ag = Aq + (size_t)(m0 + wave * 32 + (lane >> 3)) * K + sw;
  const char* Bg = Bq + (size_t)(n0 + wave * 16 + (lane >> 3)) * K + sw;
  const int nt = K >> 7;

  // prologue: stage tiles 0 and 1 (6 loads per wave per tile, FIFO order)
#pragma unroll
  for (int r8 = 0; r8 < 4; ++r8) STAGE_A8(0, 0, r8);
  STAGE_B8(0, 0, 0); STAGE_B8(0, 0, 1);
#pragma unroll
  for (int r8 = 0; r8 < 4; ++r8) STAGE_A8(1, 1, r8);
  STAGE_B8(1, 1, 0); STAGE_B8(1, 1, 1);
  asm volatile("s_waitcnt vmcnt(6)" ::: "memory");   // tile 0 resident
  __builtin_amdgcn_s_barrier();

  int cur = 0;
  for (int t = 0; t < nt; ++t) {
    const char* Ac = As[cur];
    const char* Bc = Bs[cur];
    const int nx = (cur >= 1) ? cur - 1 : 2;   // (cur+2)%3
    const bool pf = (t + 2 < nt);

    // ---- phase A: ks=0 fragments; stage first half of tile t+2
    i32x4 af0[4], bf0[4];
#pragma unroll
    for (int j = 0; j < 4; ++j)
      bf0[j] = *(const i32x4*)(Bc + (wn + j * 16 + lcol) * 128 + (lrow ^ (lcol & 7)) * 16);
#pragma unroll
    for (int i = 0; i < 4; ++i)
      af0[i] = *(const i32x4*)(Ac + (wm + i * 16 + lcol) * 128 + (lrow ^ (lcol & 7)) * 16);
    if (pf) { STAGE_A8(t + 2, nx, 0); STAGE_A8(t + 2, nx, 1); STAGE_B8(t + 2, nx, 0); }
    __builtin_amdgcn_s_barrier();
    __builtin_amdgcn_s_setprio(1);
#pragma unroll
    for (int i = 0; i < 4; ++i)
#pragma unroll
      for (int j = 0; j < 4; ++j)
        acc[i][j] = __builtin_amdgcn_mfma_i32_16x16x64_i8(af0[i], bf0[j], acc[i][j], 0, 0, 0);
    __builtin_amdgcn_s_setprio(0);
    __builtin_amdgcn_s_barrier();

    // ---- phase B: ks=1 fragments; stage second half of tile t+2; counted vmcnt
    i32x4 af1[4], bf1[4];
#pragma unroll
    for (int j = 0; j < 4; ++j)
      bf1[j] = *(const i32x4*)(Bc + (wn + j * 16 + lcol) * 128 + ((4 + lrow) ^ (lcol & 7)) * 16);
#pragma unroll
    for (int i = 0; i < 4; ++i)
      af1[i] = *(const i32x4*)(Ac + (wm + i * 16 + lcol) * 128 + ((4 + lrow) ^ (lcol & 7)) * 16);
    if (pf) { STAGE_A8(t + 2, nx, 2); STAGE_A8(t + 2, nx, 3); STAGE_B8(t + 2, nx, 1); }
    __builtin_amdgcn_s_barrier();
    __builtin_amdgcn_s_setprio(1);
#pragma unroll
    for (int i = 0; i < 4; ++i)
#pragma unroll
      for (int j = 0; j < 4; ++j)
        acc[i][j] = __builtin_amdgcn_mfma_i32_16x16x64_i8(af1[i], bf1[j], acc[i][j], 0, 0, 0);
    __builtin_amdgcn_s_setprio(0);
    if (pf) asm volatile("s_waitcnt vmcnt(6)" ::: "memory");
    else    asm volatile("s_waitcnt vmcnt(0)" ::: "memory");
    __builtin_amdgcn_s_barrier();
    cur = (cur == 2) ? 0 : cur + 1;
  }

  // epilogue: LoRA via one bf16 MFMA per tile (K=32 over hA/B2), then affine dequant
  bf16x8 ha[4], bb[4];
#pragma unroll
  for (int i = 0; i < 4; ++i) ha[i] = *(const bf16x8*)(hA + (size_t)(m0 + wm + i * 16 + lcol) * 32 + lrow * 8);
#pragma unroll
  for (int j = 0; j < 4; ++j) bb[j] = *(const bf16x8*)(B2 + (size_t)(n0 + wn + j * 16 + lcol) * 32 + lrow * 8);
  float scv[4], zpv[4], wsv[4];
#pragma unroll
  for (int j = 0; j < 4; ++j) {
    const int col = n0 + wn + j * 16 + lcol;
    scv[j] = sc[col]; zpv[j] = zp[col]; wsv[j] = wsum[col];
  }
  float smv[4][4], rsv[4][4], dev[4][4];
#pragma unroll
  for (int i = 0; i < 4; ++i)
#pragma unroll
    for (int r = 0; r < 4; ++r) {
      const int row = m0 + wm + i * 16 + lrow * 4 + r;
      smv[i][r] = s_m[row]; rsv[i][r] = rs[row]; dev[i][r] = de[row];
    }
  const f32x4 zero = {0.f, 0.f, 0.f, 0.f};
#pragma unroll
  for (int i = 0; i < 4; ++i)
#pragma unroll
    for (int j = 0; j < 4; ++j) {
      f32x4 L = __builtin_amdgcn_mfma_f32_16x16x32_bf16(ha[i], bb[j], zero, 0, 0, 0);
#pragma unroll
      for (int r = 0; r < 4; ++r) {
        const int row = m0 + wm + i * 16 + lrow * 4 + r;
        const int col = n0 + wn + j * 16 + lcol;
        const float v = scv[j] * smv[i][r] * (float)acc[i][j][r] + zpv[j] * rsv[i][r]
                      + wsv[j] * dev[i][r] + L[r];
        const size_t idx = (size_t)row * N + col;
        if (MODE == 0) Cb[idx] = (bf16)v;
        else {
          const float g = (float)gate[idx];
          Cb[idx] = (bf16)((g / (1.f + __expf(-g))) * v);
        }
      }
    }
}
#undef STAGE_A8
#undef STAGE_B8

// -------- Flash attention: Cqk [4096][4096] (q|k), VtG [(b*16+h)*128+d][2048] --------
// R10: R5-validated structure (QBLK=128, single-buffer K/V — best measured
// attn, ~143-155us) + XCD-grouped block decode.  R8 (QBLK=64, occupancy up)
// and R9 (QBLK=64 + prefetch) both landed at ~175us -> QBLK=64 family
// falsified; the per-iteration serial chain amortizes better over 128 rows.
// New: 1D grid 512, decode xcd=l&7, pi=(l>>3)&3, pair=xcd*4+pi, qt=l>>5 —
// all 16 qt-blocks of one (b,h) land on the SAME XCD (round-robin dispatch),
// so K/V (1MB per pair) become XCD-L2-resident: fewer ~900cy HBM misses on
// the staging path of a latency-bound kernel.  Bijective: 8*4*16=512.
__global__ __launch_bounds__(256) void attn_kernel(const bf16* __restrict__ Cqk,
                                                   const bf16* __restrict__ VtG,
                                                   bf16* __restrict__ obuf) {
  const int l = blockIdx.x;
  const int xcd = l & 7, pi = (l >> 3) & 3, qt = l >> 5;
  const int pair = xcd * 4 + pi;
  const int h = pair & 15, b = pair >> 4;
  const int tid = threadIdx.x, wave = tid >> 6, lane = tid & 63;
  const int lcol = lane & 15, lrow = lane >> 4;
  const int base_m = b * 2048 + qt * 128;
  __shared__ bf16 Ks[64 * 128];
  __shared__ bf16 Vt[128 * 64];
  __shared__ bf16 Ps[4][32 * 72];
  bf16* ps = Ps[wave];
  bf16x8 qf[2][4];
#pragma unroll
  for (int i = 0; i < 2; ++i)
#pragma unroll
    for (int dk = 0; dk < 4; ++dk)
      qf[i][dk] = *(const bf16x8*)(Cqk + (size_t)(base_m + wave * 32 + i * 16 + lcol) * 4096
                                   + h * 128 + dk * 32 + lrow * 8);
  f32x4 of[2][8] = {};
  float m_run[2][4], l_run[2][4];
#pragma unroll
  for (int i = 0; i < 2; ++i)
#pragma unroll
    for (int r = 0; r < 4; ++r) { m_run[i][r] = -1e30f; l_run[i][r] = 0.f; }
  const float SCL2 = 0.12751874972f;
  const int vswz = (lane & 7) ^ (lane >> 3);

  for (int kt = 0; kt < 2048; kt += 64) {
#pragma unroll
    for (int r4 = 0; r4 < 4; ++r4) {
      const int s_low = r4 * 4 + lrow;
      gl_lds16(Cqk + (size_t)(b * 2048 + kt + wave * 16 + s_low) * 4096 + 2048 + h * 128
                   + (lcol ^ s_low) * 8,
               Ks + (wave * 16 + r4 * 4) * 128);
    }
#pragma unroll
    for (int r8 = 0; r8 < 4; ++r8)
      gl_lds16(VtG + (size_t)((b * 16 + h) * 128 + wave * 32 + r8 * 8 + (lane >> 3)) * 2048
                   + kt + vswz * 8,
               Vt + (wave * 32 + r8 * 8) * 64);
    __syncthreads();

    f32x4 sacc[2][4] = {};
#pragma unroll
    for (int jb = 0; jb < 4; ++jb) {
      bf16x8 kf[4];
#pragma unroll
      for (int dk = 0; dk < 4; ++dk)
        kf[dk] = *(const bf16x8*)(Ks + (jb * 16 + lcol) * 128 + ((dk * 4 + lrow) ^ lcol) * 8);
#pragma unroll
      for (int i = 0; i < 2; ++i)
#pragma unroll
        for (int dk = 0; dk < 4; ++dk)
          sacc[i][jb] = __builtin_amdgcn_mfma_f32_16x16x32_bf16(qf[i][dk], kf[dk], sacc[i][jb], 0, 0, 0);
    }

#pragma unroll
    for (int i = 0; i < 2; ++i) {
      float z[4][4], mx[4];
#pragma unroll
      for (int jb = 0; jb < 4; ++jb)
#pragma unroll
        for (int r = 0; r < 4; ++r) z[jb][r] = sacc[i][jb][r] * SCL2;
#pragma unroll
      for (int r = 0; r < 4; ++r)
        mx[r] = fmaxf(fmaxf(z[0][r], z[1][r]), fmaxf(z[2][r], z[3][r]));
#pragma unroll
      for (int d = 1; d < 16; d <<= 1)
#pragma unroll
        for (int r = 0; r < 4; ++r) mx[r] = fmaxf(mx[r], __shfl_xor(mx[r], d));
#pragma unroll
      for (int r = 0; r < 4; ++r) {
        const float mn = fmaxf(m_run[i][r], mx[r]);
        const float alpha = __builtin_amdgcn_exp2f(m_run[i][r] - mn);
        m_run[i][r] = mn;
        float srow = 0.f;
#pragma unroll
        for (int jb = 0; jb < 4; ++jb) {
          const float p = __builtin_amdgcn_exp2f(z[jb][r] - mn);
          z[jb][r] = p; srow += p;
        }
        l_run[i][r] = l_run[i][r] * alpha + srow;
#pragma unroll
        for (int db = 0; db < 8; ++db) of[i][db][r] *= alpha;
      }
#pragma unroll
      for (int jb = 0; jb < 4; ++jb)
#pragma unroll
        for (int r = 0; r < 4; ++r)
          ps[(i * 16 + lrow * 4 + r) * 72 + jb * 16 + lcol] = (bf16)z[jb][r];
    }

#pragma unroll
    for (int ss = 0; ss < 2; ++ss) {
      bf16x8 a0 = *(const bf16x8*)(ps + (0 * 16 + lcol) * 72 + ss * 32 + lrow * 8);
      bf16x8 a1 = *(const bf16x8*)(ps + (1 * 16 + lcol) * 72 + ss * 32 + lrow * 8);
#pragma unroll
      for (int db = 0; db < 8; ++db) {
        bf16x8 vf = *(const bf16x8*)(Vt + (db * 16 + lcol) * 64 + ((ss * 4 + lrow) ^ (lcol & 7)) * 8);
        of[0][db] = __builtin_amdgcn_mfma_f32_16x16x32_bf16(a0, vf, of[0][db], 0, 0, 0);
        of[1][db] = __builtin_amdgcn_mfma_f32_16x16x32_bf16(a1, vf, of[1][db], 0, 0, 0);
      }
    }
    __syncthreads();
  }
#pragma unroll
  for (int i = 0; i < 2; ++i)
#pragma unroll
    for (int r = 0; r < 4; ++r) {
      float l2 = l_run[i][r];
#pragma unroll
      for (int d = 1; d < 16; d <<= 1) l2 += __shfl_xor(l2, d);
      const float inv = 1.f / l2;
      const size_t rb = (size_t)(base_m + wave * 32 + i * 16 + lrow * 4 + r) * 2048 + h * 128;
#pragma unroll
      for (int db = 0; db < 8; ++db)
        obuf[rb + db * 16 + lcol] = (bf16)(of[i][db][r] * inv);
    }
}

extern "C" void kernel_launch(void* const* d_in, const int* in_sizes, int n_in,
                              void* d_out, int out_size, void* d_ws, size_t ws_size,
                              hipStream_t stream) {
  (void)in_sizes; (void)n_in; (void)out_size; (void)ws_size;
  const int*   q_qw = (const int*)d_in[0];   const float* q_sc = (const float*)d_in[1];
  const float* q_zp = (const float*)d_in[2]; const float* q_A  = (const float*)d_in[3];
  const float* q_B  = (const float*)d_in[4];
  const int*   k_qw = (const int*)d_in[5];   const float* k_sc = (const float*)d_in[6];
  const float* k_zp = (const float*)d_in[7]; const float* k_A  = (const float*)d_in[8];
  const float* k_B  = (const float*)d_in[9];
  const int*   v_qw = (const int*)d_in[10];  const float* v_sc = (const float*)d_in[11];
  const float* v_zp = (const float*)d_in[12];const float* v_A  = (const float*)d_in[13];
  const float* v_B  = (const float*)d_in[14];
  const int*   o_qw = (const int*)d_in[15];  const float* o_sc = (const float*)d_in[16];
  const float* o_zp = (const float*)d_in[17];const float* o_A  = (const float*)d_in[18];
  const float* o_B  = (const float*)d_in[19];
  const int*   g_qw = (const int*)d_in[20];  const float* g_sc = (const float*)d_in[21];
  const float* g_zp = (const float*)d_in[22];const float* g_A  = (const float*)d_in[23];
  const float* g_B  = (const float*)d_in[24];
  const int*   u_qw = (const int*)d_in[25];  const float* u_sc = (const float*)d_in[26];
  const float* u_zp = (const float*)d_in[27];const float* u_A  = (const float*)d_in[28];
  const float* u_B  = (const float*)d_in[29];
  const int*   d_qw = (const int*)d_in[30];  const float* d_sc = (const float*)d_in[31];
  const float* d_zp = (const float*)d_in[32];const float* d_A  = (const float*)d_in[33];
  const float* d_B  = (const float*)d_in[34];
  const float* x    = (const float*)d_in[35];
  const float* ln1w = (const float*)d_in[36];const float* ln1b = (const float*)d_in[37];
  const float* ln2w = (const float*)d_in[38];const float* ln2b = (const float*)d_in[39];

  // workspace arena — peak 112 MiB.  x1 lives in d_out (fp32).
  char* ws = (char*)d_ws;
  bf16* W = (bf16*)ws;                                    // 32 MiB dequant scratch (qkv/o/d)
  char* Wg8 = ws;                                         // FFN phase: int8 g-weights
  char* Wu8 = ws + (size_t)8192 * 2048;                   //            int8 u-weights
  char* p2  = ws + (size_t)32 * 1024 * 1024;              // 16 MiB region
  bf16* h   = (bf16*)p2;                                  // LN1 out (dead after qkv GEMM)
  char*  qh  = p2;                                        // FFN phase: int8 LN2 out (8.39 MB)
  float* s_m = (float*)(p2 + 8 * 1024 * 1024);            // 16 KB
  float* rs  = (float*)(p2 + 8 * 1024 * 1024 + 16384);    // 16 KB
  float* de  = (float*)(p2 + 8 * 1024 * 1024 + 32768);    // 16 KB
  bf16*  hA  = (bf16*)(p2 + 8 * 1024 * 1024 + 49152);     // 256 KB
  bf16*  B2g = (bf16*)(p2 + 8 * 1024 * 1024 + 49152 + 262144);  // 512 KB
  bf16*  B2u = B2g + (size_t)8192 * 32;                   // 512 KB
  float* wsg = (float*)((char*)(B2u + (size_t)8192 * 32));      // 32 KB
  float* wsu = wsg + 8192;                                // 32 KB
  bf16* C = (bf16*)(ws + (size_t)48 * 1024 * 1024);       // 64 MiB
  bf16* Cqk = C;                                          // [4096][4096] q|k
  bf16* VtG = C + (size_t)4096 * 4096;                    // [2*16*128][2048]
  bf16* obuf = VtG + (size_t)2 * 16 * 128 * 2048;         // [4096][2048]
  float* x1  = (float*)d_out;
  float* out = (float*)d_out;

  // 1. h = LN1(x)
  ln_kernel<<<4096, 256, 0, stream>>>(x, ln1w, ln1b, h);
  // 2. dequant W_q|W_k|W_v (6144x2048), single merged launch
  dequant3_kernel<<<6144, 256, 0, stream>>>(q_qw, q_sc, q_zp, q_A, q_B,
                                            k_qw, k_sc, k_zp, k_A, k_B,
                                            v_qw, v_sc, v_zp, v_A, v_B, W);
  // 3. qkv GEMM: q|k -> Cqk, v -> VtG (transposed packed stores)
  gemm8_kernel<3><<<dim3(48, 16), 512, 0, stream>>>(h, W, Cqk, nullptr, nullptr, VtG, 4096, 6144, 2048, 4096);
  // 4. attention (R5 form, XCD-grouped 1D grid of 512)
  attn_kernel<<<512, 256, 0, stream>>>(Cqk, VtG, obuf);
  // 5-6. x1 = x + o @ W_o^T
  dequant_kernel<<<2048, 256, 0, stream>>>(o_qw, o_sc, o_zp, o_A, o_B, W, 2048, 2048);
  gemm8_kernel<1><<<dim3(16, 16), 512, 0, stream>>>(obuf, W, nullptr, x1, x, nullptr, 4096, 2048, 2048, 2048);
  // 7. LN2 + int8 quantize (h region dead; reuse for qh/s_m/rs/de/hA/B2/wsum)
  ln_q_kernel<<<4096, 256, 0, stream>>>(x1, ln2w, ln2b, qh, s_m, rs, de);
  // 8. FFN LoRA/weight prep (W bf16 region dead; reuse for int8 weights)
  hA_kernel<<<1024, 256, 0, stream>>>(qh, s_m, g_A, u_A, hA);
  pack_w_kernel<<<8192, 256, 0, stream>>>(g_qw, g_sc, Wg8, wsg);
  pack_w_kernel<<<8192, 256, 0, stream>>>(u_qw, u_sc, Wu8, wsu);
  pack_b2_kernel<<<1024, 256, 0, stream>>>(g_B, u_B, B2g, B2u);
  // 9. g = dequant-epilogue(qh @ Wg8^T) -> C
  gemm_i8_kernel<0><<<dim3(64, 16), 512, 0, stream>>>(qh, Wg8, s_m, rs, de, g_sc, g_zp, wsg, hA, B2g, C, nullptr, 4096, 8192, 2048);
  // 10. ff = silu(g) * (qh @ Wu8^T dequant), in-place over C
  gemm_i8_kernel<1><<<dim3(64, 16), 512, 0, stream>>>(qh, Wu8, s_m, rs, de, u_sc, u_zp, wsu, hA, B2u, C, C, 4096, 8192, 2048);
  // 11-12. out = x1 + ff @ W_d^T (bf16 path)
  dequant_kernel<<<8192, 256, 0, stream>>>(d_qw, d_sc, d_zp, d_A, d_B, W, 2048, 8192);
  gemm8_kernel<1><<<dim3(16, 16), 512, 0, stream>>>(C, W, nullptr, out, x1, nullptr, 4096, 2048, 8192, 2048);
}

// Round 11
// 1118.442 us; speedup vs baseline: 1.0639x; 1.0639x over previous
//
#include <hip/hip_runtime.h>
#include <cstdint>
#include <cstddef>

#define GLOBAL_AS __attribute__((address_space(1)))
#define LDS_AS    __attribute__((address_space(3)))

typedef __bf16 bf16;
typedef __bf16 bf16x4 __attribute__((ext_vector_type(4)));
typedef __bf16 bf16x8 __attribute__((ext_vector_type(8)));
typedef float  f32x4  __attribute__((ext_vector_type(4)));
typedef int    i32x4  __attribute__((ext_vector_type(4)));
typedef unsigned int u32x2 __attribute__((ext_vector_type(2)));

__device__ __forceinline__ void gl_lds16(const void* g, void* l) {
  // 16B-per-lane async global->LDS; LDS dest = wave-uniform base + lane*16
  __builtin_amdgcn_global_load_lds((GLOBAL_AS void*)g, (LDS_AS void*)l, 16, 0, 0);
}

// ---------------- LayerNorm: fp32 (rows of 2048) -> bf16 ----------------
__global__ __launch_bounds__(256) void ln_kernel(const float* __restrict__ x,
                                                 const float* __restrict__ w,
                                                 const float* __restrict__ bias,
                                                 bf16* __restrict__ out) {
  const int row = blockIdx.x;
  const int tid = threadIdx.x;
  const float* xr = x + (size_t)row * 2048;
  f32x4 v0 = ((const f32x4*)xr)[tid * 2];
  f32x4 v1 = ((const f32x4*)xr)[tid * 2 + 1];
  float s = 0.f, ss = 0.f;
#pragma unroll
  for (int j = 0; j < 4; ++j) { s += v0[j]; ss += v0[j] * v0[j]; }
#pragma unroll
  for (int j = 0; j < 4; ++j) { s += v1[j]; ss += v1[j] * v1[j]; }
#pragma unroll
  for (int d = 1; d < 64; d <<= 1) { s += __shfl_xor(s, d); ss += __shfl_xor(ss, d); }
  __shared__ float red[8];
  const int wave = tid >> 6, lane = tid & 63;
  if (lane == 0) { red[wave * 2] = s; red[wave * 2 + 1] = ss; }
  __syncthreads();
  s  = red[0] + red[2] + red[4] + red[6];
  ss = red[1] + red[3] + red[5] + red[7];
  const float mean = s * (1.f / 2048.f);
  const float var  = ss * (1.f / 2048.f) - mean * mean;  // biased, matches jnp var
  const float rstd = rsqrtf(var + 1e-5f);
  const int col = tid * 8;
  bf16x8 o;
#pragma unroll
  for (int j = 0; j < 4; ++j) o[j]     = (bf16)((v0[j] - mean) * rstd * w[col + j]     + bias[col + j]);
#pragma unroll
  for (int j = 0; j < 4; ++j) o[4 + j] = (bf16)((v1[j] - mean) * rstd * w[col + 4 + j] + bias[col + 4 + j]);
  *(bf16x8*)(out + (size_t)row * 2048 + col) = o;
}

// ---------------- LayerNorm + int8 row-quantize (for i8 GEMM path) ----------------
__global__ __launch_bounds__(256) void ln_q_kernel(const float* __restrict__ x,
    const float* __restrict__ w, const float* __restrict__ bias,
    char* __restrict__ qh, float* __restrict__ s_m, float* __restrict__ rs,
    float* __restrict__ de) {
  const int row = blockIdx.x;
  const int tid = threadIdx.x;
  const float* xr = x + (size_t)row * 2048;
  f32x4 v0 = ((const f32x4*)xr)[tid * 2];
  f32x4 v1 = ((const f32x4*)xr)[tid * 2 + 1];
  float s = 0.f, ss = 0.f;
#pragma unroll
  for (int j = 0; j < 4; ++j) { s += v0[j]; ss += v0[j] * v0[j]; }
#pragma unroll
  for (int j = 0; j < 4; ++j) { s += v1[j]; ss += v1[j] * v1[j]; }
#pragma unroll
  for (int d = 1; d < 64; d <<= 1) { s += __shfl_xor(s, d); ss += __shfl_xor(ss, d); }
  __shared__ float red[12];
  const int wave = tid >> 6, lane = tid & 63;
  if (lane == 0) { red[wave * 2] = s; red[wave * 2 + 1] = ss; }
  __syncthreads();
  s  = red[0] + red[2] + red[4] + red[6];
  ss = red[1] + red[3] + red[5] + red[7];
  const float mean = s * (1.f / 2048.f);
  const float var  = ss * (1.f / 2048.f) - mean * mean;
  const float rstd = rsqrtf(var + 1e-5f);
  const int col = tid * 8;
  float y[8];
#pragma unroll
  for (int j = 0; j < 4; ++j) y[j]     = (v0[j] - mean) * rstd * w[col + j]     + bias[col + j];
#pragma unroll
  for (int j = 0; j < 4; ++j) y[4 + j] = (v1[j] - mean) * rstd * w[col + 4 + j] + bias[col + 4 + j];
  float sy = 0.f, mx = 0.f;
#pragma unroll
  for (int j = 0; j < 8; ++j) { sy += y[j]; mx = fmaxf(mx, fabsf(y[j])); }
#pragma unroll
  for (int d = 1; d < 64; d <<= 1) { sy += __shfl_xor(sy, d); mx = fmaxf(mx, __shfl_xor(mx, d)); }
  __syncthreads();  // red reuse
  if (lane == 0) { red[wave * 2] = sy; red[wave * 2 + 1] = mx; }
  __syncthreads();
  const float sya = red[0] + red[2] + red[4] + red[6];
  const float mxa = fmaxf(fmaxf(red[1], red[3]), fmaxf(red[5], red[7]));
  const float inv = 127.f / fmaxf(mxa, 1e-8f);
  unsigned int lo = 0, hi = 0;
  int qs = 0;
#pragma unroll
  for (int j = 0; j < 4; ++j) { int qi = (int)rintf(y[j] * inv);     qs += qi; lo |= ((unsigned int)qi & 0xffu) << (8 * j); }
#pragma unroll
  for (int j = 0; j < 4; ++j) { int qi = (int)rintf(y[4 + j] * inv); qs += qi; hi |= ((unsigned int)qi & 0xffu) << (8 * j); }
  u32x2 st; st[0] = lo; st[1] = hi;
  *(u32x2*)(qh + (size_t)row * 2048 + col) = st;
  float fqs = (float)qs;
#pragma unroll
  for (int d = 1; d < 64; d <<= 1) fqs += __shfl_xor(fqs, d);
  __syncthreads();
  if (lane == 0) red[8 + wave] = fqs;
  __syncthreads();
  if (tid == 0) {
    const float qsa = red[8] + red[9] + red[10] + red[11];
    const float smv = fmaxf(mxa, 1e-8f) / 127.f;
    s_m[row] = smv; rs[row] = sya; de[row] = sya - smv * qsa;
  }
}

// -------- Dequant + LoRA fold: W[o,i] = qw*sc[o]+zp[o]+2*(B@A)[o,i] --------
__device__ __forceinline__ void dequant_body(const int* qw, const float* sc,
    const float* zp, const float* A, const float* Bm, bf16* W, int in_f,
    int bid, int tid) {
  const int per_row = in_f >> 3;
  const int idx = bid * 256 + tid;
  const int o  = idx / per_row;
  const int i0 = (idx - o * per_row) << 3;
  const float s = sc[o], z = zp[o];
  float bl[16];
#pragma unroll
  for (int r = 0; r < 16; ++r) bl[r] = Bm[o * 16 + r];
  float acc[8] = {0.f, 0.f, 0.f, 0.f, 0.f, 0.f, 0.f, 0.f};
#pragma unroll
  for (int r = 0; r < 16; ++r) {
    const f32x4* ap = (const f32x4*)(A + (size_t)r * in_f + i0);
    f32x4 a0 = ap[0], a1 = ap[1];
#pragma unroll
    for (int j = 0; j < 4; ++j) { acc[j] += bl[r] * a0[j]; acc[4 + j] += bl[r] * a1[j]; }
  }
  const int* qp = qw + (size_t)o * in_f + i0;
  bf16x8 w8;
#pragma unroll
  for (int j = 0; j < 8; ++j) w8[j] = (bf16)((float)qp[j] * s + z + 2.f * acc[j]);
  *(bf16x8*)(W + (size_t)o * in_f + i0) = w8;
}

__global__ __launch_bounds__(256) void dequant_kernel(const int* __restrict__ qw,
    const float* __restrict__ sc, const float* __restrict__ zp,
    const float* __restrict__ A, const float* __restrict__ Bm,
    bf16* __restrict__ W, int out_f, int in_f) {
  dequant_body(qw, sc, zp, A, Bm, W, in_f, blockIdx.x, threadIdx.x);
}

// merged q|k|v dequant: 6144 blocks, segment = blockIdx>>11
__global__ __launch_bounds__(256) void dequant3_kernel(
    const int* q_qw, const float* q_sc, const float* q_zp, const float* q_A, const float* q_B,
    const int* k_qw, const float* k_sc, const float* k_zp, const float* k_A, const float* k_B,
    const int* v_qw, const float* v_sc, const float* v_zp, const float* v_A, const float* v_B,
    bf16* W) {
  const int seg = blockIdx.x >> 11;
  const int bid = blockIdx.x & 2047;
  const int* qw = (seg == 0) ? q_qw : (seg == 1) ? k_qw : v_qw;
  const float* sc = (seg == 0) ? q_sc : (seg == 1) ? k_sc : v_sc;
  const float* zp = (seg == 0) ? q_zp : (seg == 1) ? k_zp : v_zp;
  const float* A  = (seg == 0) ? q_A  : (seg == 1) ? k_A  : v_A;
  const float* Bm = (seg == 0) ? q_B  : (seg == 1) ? k_B  : v_B;
  dequant_body(qw, sc, zp, A, Bm, W + (size_t)seg * 2048 * 2048, 2048, bid, threadIdx.x);
}

// -------- int32 -> int8 weight pack + per-row mean weight (one 2048-row per block) --------
__global__ __launch_bounds__(256) void pack_w_kernel(const int* __restrict__ qw,
    const float* __restrict__ sc, char* __restrict__ out, float* __restrict__ wsum) {
  const int row = blockIdx.x;
  const int tid = threadIdx.x;
  const size_t idx = (size_t)row * 2048 + tid * 8;
  i32x4 a = *(const i32x4*)(qw + idx);
  i32x4 b = *(const i32x4*)(qw + idx + 4);
  unsigned int lo = ((unsigned)a[0] & 0xffu) | (((unsigned)a[1] & 0xffu) << 8) |
                    (((unsigned)a[2] & 0xffu) << 16) | (((unsigned)a[3] & 0xffu) << 24);
  unsigned int hi = ((unsigned)b[0] & 0xffu) | (((unsigned)b[1] & 0xffu) << 8) |
                    (((unsigned)b[2] & 0xffu) << 16) | (((unsigned)b[3] & 0xffu) << 24);
  u32x2 st; st[0] = lo; st[1] = hi;
  *(u32x2*)(out + idx) = st;
  float fs = (float)(a[0] + a[1] + a[2] + a[3] + b[0] + b[1] + b[2] + b[3]);
#pragma unroll
  for (int d = 1; d < 64; d <<= 1) fs += __shfl_xor(fs, d);
  __shared__ float red[4];
  const int wave = tid >> 6, lane = tid & 63;
  if (lane == 0) red[wave] = fs;
  __syncthreads();
  if (tid == 0) wsum[row] = sc[row] * (red[0] + red[1] + red[2] + red[3]) * (1.f / 2048.f);
}

// -------- LoRA B matrices -> bf16 [N][32], x2 scale, zero-padded per matrix --------
__global__ __launch_bounds__(256) void pack_b2_kernel(const float* __restrict__ gB,
    const float* __restrict__ uB, bf16* __restrict__ B2g, bf16* __restrict__ B2u) {
  const int idx = blockIdx.x * 256 + threadIdx.x;   // 8192*32
  const int nn = idx >> 5, r = idx & 31;
  B2g[idx] = (r < 16)  ? (bf16)(2.f * gB[nn * 16 + r])        : (bf16)0.f;
  B2u[idx] = (r >= 16) ? (bf16)(2.f * uB[nn * 16 + (r - 16)]) : (bf16)0.f;
}

// -------- hA[m][0..32) = s_m * (qh @ [Ag|Au].T), bf16 --------
__global__ __launch_bounds__(256) void hA_kernel(const char* __restrict__ qh,
    const float* __restrict__ s_m, const float* __restrict__ Ag,
    const float* __restrict__ Au, bf16* __restrict__ hA) {
  __shared__ bf16 Asm[32 * 512];
  const int tid = threadIdx.x, wave = tid >> 6, lane = tid & 63;
  const int row = blockIdx.x * 4 + wave;
  float acc[32];
#pragma unroll
  for (int r = 0; r < 32; ++r) acc[r] = 0.f;
  for (int kb = 0; kb < 2048; kb += 512) {
    const int r2 = tid >> 3, c0 = (tid & 7) * 64;
    const float* src = (r2 < 16 ? Ag + (size_t)r2 * 2048 : Au + (size_t)(r2 - 16) * 2048) + kb + c0;
#pragma unroll
    for (int j = 0; j < 64; j += 8) {
      f32x4 va = *(const f32x4*)(src + j);
      f32x4 vb = *(const f32x4*)(src + j + 4);
      bf16x8 bv;
#pragma unroll
      for (int jj = 0; jj < 4; ++jj) { bv[jj] = (bf16)va[jj]; bv[4 + jj] = (bf16)vb[jj]; }
      *(bf16x8*)(Asm + r2 * 512 + c0 + j) = bv;
    }
    __syncthreads();
    float q[8];
    const char* qp = qh + (size_t)row * 2048 + kb + lane * 8;
#pragma unroll
    for (int j = 0; j < 8; ++j) q[j] = (float)qp[j];
#pragma unroll
    for (int r = 0; r < 32; ++r) {
      bf16x8 a8 = *(const bf16x8*)(Asm + r * 512 + lane * 8);
      float d = 0.f;
#pragma unroll
      for (int j = 0; j < 8; ++j) d += q[j] * (float)a8[j];
      acc[r] += d;
    }
    __syncthreads();
  }
  const float s = s_m[row];
#pragma unroll
  for (int r = 0; r < 32; ++r) {
    float v = acc[r];
#pragma unroll
    for (int d = 1; d < 64; d <<= 1) v += __shfl_xor(v, d);
    if (lane == 0) hA[(size_t)row * 32 + r] = (bf16)(s * v);
  }
}

// -------- bf16 GEMM, pipelined (round-2 validated form): C = A @ B^T --------
// 256x128 tile, BK=64, 8 waves (4M x 2N, per-wave 64x64), triple-buffered LDS,
// counted s_waitcnt vmcnt(6), setprio around MFMA, XCD-chunked block swizzle.
// 2 phases per K-tile (ks-half split), each: {8 ds_read_b128 + 3 stage loads ->
// barrier -> setprio -> 16 MFMA -> setprio -> barrier}.  MFMA:barrier = 8.
// VALIDATED: R1 (ratio 4) = 189.8us, R2 (this, ratio 8) = 158.9us, R3
// (1 barrier/K-tile) = 188.8us -> barrier alternation of the 2 waves/SIMD is
// load-bearing.  Structural ceiling for 64x64/wave ~= 42% MfmaUtil (LDS port
// and MFMA serialize across the barrier); measured 38%.
#define STAGE_A(t, buf, r8) gl_lds16(Ag + (size_t)(r8) * 8 * K + (size_t)(t) * 64, \
                                     &As[buf][((wave * 32) + (r8) * 8) * 64])
#define STAGE_B(t, buf, r8) gl_lds16(Bg + (size_t)(r8) * 8 * K + (size_t)(t) * 64, \
                                     &Bs[buf][((wave * 16) + (r8) * 8) * 64])

template <int MODE>
__global__ __launch_bounds__(512, 2) void gemm8_kernel(const bf16* __restrict__ A,
    const bf16* __restrict__ B, bf16* __restrict__ Cb, float* __restrict__ Cf,
    const float* __restrict__ res, bf16* __restrict__ vt,
    int M, int N, int K, int ldc) {
  const int tid = threadIdx.x;
  const int wave = tid >> 6, lane = tid & 63;
  const int lcol = lane & 15, lrow = lane >> 4;
  const int wm = (wave >> 1) * 64, wn = (wave & 1) * 64;
  // XCD-aware swizzle (all grids here are multiples of 8 blocks)
  const int nwg = gridDim.x * gridDim.y;
  const int bid = blockIdx.y * gridDim.x + blockIdx.x;
  const int swb = (bid & 7) * (nwg >> 3) + (bid >> 3);
  const int n0 = (swb % gridDim.x) * 128;
  const int m0 = (swb / gridDim.x) * 256;
  __shared__ bf16 As[3][256 * 64];   // 96 KiB
  __shared__ bf16 Bs[3][128 * 64];   // 48 KiB
  f32x4 acc[4][4] = {};
  const int sw = ((lane & 7) ^ ((lane >> 3) & 7)) * 8;
  const bf16* Ag = A + (size_t)(m0 + wave * 32 + (lane >> 3)) * K + sw;
  const bf16* Bg = B + (size_t)(n0 + wave * 16 + (lane >> 3)) * K + sw;
  const int nt = K >> 6;

  // prologue: stage tiles 0 and 1 (6 loads per wave per tile, FIFO order)
#pragma unroll
  for (int r8 = 0; r8 < 4; ++r8) STAGE_A(0, 0, r8);
  STAGE_B(0, 0, 0); STAGE_B(0, 0, 1);
#pragma unroll
  for (int r8 = 0; r8 < 4; ++r8) STAGE_A(1, 1, r8);
  STAGE_B(1, 1, 0); STAGE_B(1, 1, 1);
  asm volatile("s_waitcnt vmcnt(6)" ::: "memory");   // tile 0 resident
  __builtin_amdgcn_s_barrier();

  int cur = 0;
  for (int t = 0; t < nt; ++t) {
    const bf16* Ac = As[cur];
    const bf16* Bc = Bs[cur];
    const int nx = (cur >= 1) ? cur - 1 : 2;   // (cur+2)%3
    const bool pf = (t + 2 < nt);

    // ---- phase A: ks=0 fragments; stage first half of tile t+2
    bf16x8 a0[4], b0[4];
#pragma unroll
    for (int j = 0; j < 4; ++j)
      b0[j] = *(const bf16x8*)(Bc + (wn + j * 16 + lcol) * 64 + (lrow ^ (lcol & 7)) * 8);
#pragma unroll
    for (int i = 0; i < 4; ++i)
      a0[i] = *(const bf16x8*)(Ac + (wm + i * 16 + lcol) * 64 + (lrow ^ (lcol & 7)) * 8);
    if (pf) { STAGE_A(t + 2, nx, 0); STAGE_A(t + 2, nx, 1); STAGE_B(t + 2, nx, 0); }
    __builtin_amdgcn_s_barrier();
    __builtin_amdgcn_s_setprio(1);
#pragma unroll
    for (int i = 0; i < 4; ++i)
#pragma unroll
      for (int j = 0; j < 4; ++j)
        acc[i][j] = __builtin_amdgcn_mfma_f32_16x16x32_bf16(a0[i], b0[j], acc[i][j], 0, 0, 0);
    __builtin_amdgcn_s_setprio(0);
    __builtin_amdgcn_s_barrier();

    // ---- phase B: ks=1 fragments; stage second half of tile t+2; counted vmcnt
    bf16x8 a1[4], b1[4];
#pragma unroll
    for (int j = 0; j < 4; ++j)
      b1[j] = *(const bf16x8*)(Bc + (wn + j * 16 + lcol) * 64 + ((4 + lrow) ^ (lcol & 7)) * 8);
#pragma unroll
    for (int i = 0; i < 4; ++i)
      a1[i] = *(const bf16x8*)(Ac + (wm + i * 16 + lcol) * 64 + ((4 + lrow) ^ (lcol & 7)) * 8);
    if (pf) { STAGE_A(t + 2, nx, 2); STAGE_A(t + 2, nx, 3); STAGE_B(t + 2, nx, 1); }
    __builtin_amdgcn_s_barrier();
    __builtin_amdgcn_s_setprio(1);
#pragma unroll
    for (int i = 0; i < 4; ++i)
#pragma unroll
      for (int j = 0; j < 4; ++j)
        acc[i][j] = __builtin_amdgcn_mfma_f32_16x16x32_bf16(a1[i], b1[j], acc[i][j], 0, 0, 0);
    __builtin_amdgcn_s_setprio(0);
    // wait for tile t+1 only; leave t+2's 6 loads in flight (never drain to 0
    // in steady state)
    if (pf) asm volatile("s_waitcnt vmcnt(6)" ::: "memory");
    else    asm volatile("s_waitcnt vmcnt(0)" ::: "memory");
    __builtin_amdgcn_s_barrier();
    cur = (cur == 2) ? 0 : cur + 1;
  }

  // epilogue (same per-frag mapping as the verified 128^2 kernel)
#pragma unroll
  for (int i = 0; i < 4; ++i)
#pragma unroll
    for (int j = 0; j < 4; ++j) {
      const int row0 = m0 + wm + i * 16 + lrow * 4;
      const int col  = n0 + wn + j * 16 + lcol;
      if (MODE == 3 && col >= 4096) {
        const int c2 = col - 4096;
        bf16x4 v4;
#pragma unroll
        for (int r = 0; r < 4; ++r) v4[r] = (bf16)acc[i][j][r];
        *(bf16x4*)(vt + (size_t)(((row0 >> 11) * 16 + (c2 >> 7)) * 128 + (c2 & 127)) * 2048
                      + (row0 & 2047)) = v4;
      } else {
#pragma unroll
        for (int r = 0; r < 4; ++r) {
          const int row = row0 + r;
          const float v = acc[i][j][r];
          const size_t idx = (size_t)row * ldc + col;
          if (MODE == 1) Cf[idx] = res[idx] + v;
          else           Cb[idx] = (bf16)v;
        }
      }
    }
}
#undef STAGE_A
#undef STAGE_B

// -------- int8 GEMM, pipelined (same structure as bf16 winner): --------
// 256x128 tile, BK=128 bytes, 8 waves 4M x 2N, triple-buffered LDS (144 KiB),
// counted vmcnt(6), 2 phases/K-tile with 16 mfma_i32_16x16x64_i8 each.
// Epilogue: out[m,o] = sc[o]*s_m[m]*(qh@qw^T) + zp[o]*rs[m] + wsum[o]*de[m]
//           + (hA@B2^T).  MODE 0: bf16 store.  MODE 1: silu(gate)*val.
#define STAGE_A8(t, buf, r8) gl_lds16(Ag + (size_t)(r8) * 8 * K + (size_t)(t) * 128, \
                                      &As[buf][((wave * 32) + (r8) * 8) * 128])
#define STAGE_B8(t, buf, r8) gl_lds16(Bg + (size_t)(r8) * 8 * K + (size_t)(t) * 128, \
                                      &Bs[buf][((wave * 16) + (r8) * 8) * 128])

template <int MODE>
__global__ __launch_bounds__(512, 2) void gemm_i8_kernel(const char* __restrict__ Aq,
    const char* __restrict__ Bq, const float* __restrict__ s_m, const float* __restrict__ rs,
    const float* __restrict__ de, const float* __restrict__ sc, const float* __restrict__ zp,
    const float* __restrict__ wsum, const bf16* __restrict__ hA, const bf16* __restrict__ B2,
    bf16* __restrict__ Cb, const bf16* __restrict__ gate, int M, int N, int K) {
  const int tid = threadIdx.x;
  const int wave = tid >> 6, lane = tid & 63;
  const int lcol = lane & 15, lrow = lane >> 4;
  const int wm = (wave >> 1) * 64, wn = (wave & 1) * 64;
  // XCD-aware swizzle (grid 64x16 = 1024 blocks, %8==0)
  const int nwg = gridDim.x * gridDim.y;
  const int bid = blockIdx.y * gridDim.x + blockIdx.x;
  const int swb = (bid & 7) * (nwg >> 3) + (bid >> 3);
  const int n0 = (swb % gridDim.x) * 128;
  const int m0 = (swb / gridDim.x) * 256;
  __shared__ char As[3][256 * 128];   // 96 KiB
  __shared__ char Bs[3][128 * 128];   // 48 KiB
  i32x4 acc[4][4] = {};
  const int sw = ((lane & 7) ^ ((lane >> 3) & 7)) * 16;   // byte swizzle, 16B chunks
  const char* Ag = Aq + (size_t)(m0 + wave * 32 + (lane >> 3)) * K + sw;
  const char* Bg = Bq + (size_t)(n0 + wave * 16 + (lane >> 3)) * K + sw;
  const int nt = K >> 7;

  // prologue: stage tiles 0 and 1 (6 loads per wave per tile, FIFO order)
#pragma unroll
  for (int r8 = 0; r8 < 4; ++r8) STAGE_A8(0, 0, r8);
  STAGE_B8(0, 0, 0); STAGE_B8(0, 0, 1);
#pragma unroll
  for (int r8 = 0; r8 < 4; ++r8) STAGE_A8(1, 1, r8);
  STAGE_B8(1, 1, 0); STAGE_B8(1, 1, 1);
  asm volatile("s_waitcnt vmcnt(6)" ::: "memory");   // tile 0 resident
  __builtin_amdgcn_s_barrier();

  int cur = 0;
  for (int t = 0; t < nt; ++t) {
    const char* Ac = As[cur];
    const char* Bc = Bs[cur];
    const int nx = (cur >= 1) ? cur - 1 : 2;   // (cur+2)%3
    const bool pf = (t + 2 < nt);

    // ---- phase A: ks=0 fragments; stage first half of tile t+2
    i32x4 af0[4], bf0[4];
#pragma unroll
    for (int j = 0; j < 4; ++j)
      bf0[j] = *(const i32x4*)(Bc + (wn + j * 16 + lcol) * 128 + (lrow ^ (lcol & 7)) * 16);
#pragma unroll
    for (int i = 0; i < 4; ++i)
      af0[i] = *(const i32x4*)(Ac + (wm + i * 16 + lcol) * 128 + (lrow ^ (lcol & 7)) * 16);
    if (pf) { STAGE_A8(t + 2, nx, 0); STAGE_A8(t + 2, nx, 1); STAGE_B8(t + 2, nx, 0); }
    __builtin_amdgcn_s_barrier();
    __builtin_amdgcn_s_setprio(1);
#pragma unroll
    for (int i = 0; i < 4; ++i)
#pragma unroll
      for (int j = 0; j < 4; ++j)
        acc[i][j] = __builtin_amdgcn_mfma_i32_16x16x64_i8(af0[i], bf0[j], acc[i][j], 0, 0, 0);
    __builtin_amdgcn_s_setprio(0);
    __builtin_amdgcn_s_barrier();

    // ---- phase B: ks=1 fragments; stage second half of tile t+2; counted vmcnt
    i32x4 af1[4], bf1[4];
#pragma unroll
    for (int j = 0; j < 4; ++j)
      bf1[j] = *(const i32x4*)(Bc + (wn + j * 16 + lcol) * 128 + ((4 + lrow) ^ (lcol & 7)) * 16);
#pragma unroll
    for (int i = 0; i < 4; ++i)
      af1[i] = *(const i32x4*)(Ac + (wm + i * 16 + lcol) * 128 + ((4 + lrow) ^ (lcol & 7)) * 16);
    if (pf) { STAGE_A8(t + 2, nx, 2); STAGE_A8(t + 2, nx, 3); STAGE_B8(t + 2, nx, 1); }
    __builtin_amdgcn_s_barrier();
    __builtin_amdgcn_s_setprio(1);
#pragma unroll
    for (int i = 0; i < 4; ++i)
#pragma unroll
      for (int j = 0; j < 4; ++j)
        acc[i][j] = __builtin_amdgcn_mfma_i32_16x16x64_i8(af1[i], bf1[j], acc[i][j], 0, 0, 0);
    __builtin_amdgcn_s_setprio(0);
    if (pf) asm volatile("s_waitcnt vmcnt(6)" ::: "memory");
    else    asm volatile("s_waitcnt vmcnt(0)" ::: "memory");
    __builtin_amdgcn_s_barrier();
    cur = (cur == 2) ? 0 : cur + 1;
  }

  // epilogue: LoRA via one bf16 MFMA per tile (K=32 over hA/B2), then affine dequant
  bf16x8 ha[4], bb[4];
#pragma unroll
  for (int i = 0; i < 4; ++i) ha[i] = *(const bf16x8*)(hA + (size_t)(m0 + wm + i * 16 + lcol) * 32 + lrow * 8);
#pragma unroll
  for (int j = 0; j < 4; ++j) bb[j] = *(const bf16x8*)(B2 + (size_t)(n0 + wn + j * 16 + lcol) * 32 + lrow * 8);
  float scv[4], zpv[4], wsv[4];
#pragma unroll
  for (int j = 0; j < 4; ++j) {
    const int col = n0 + wn + j * 16 + lcol;
    scv[j] = sc[col]; zpv[j] = zp[col]; wsv[j] = wsum[col];
  }
  float smv[4][4], rsv[4][4], dev[4][4];
#pragma unroll
  for (int i = 0; i < 4; ++i)
#pragma unroll
    for (int r = 0; r < 4; ++r) {
      const int row = m0 + wm + i * 16 + lrow * 4 + r;
      smv[i][r] = s_m[row]; rsv[i][r] = rs[row]; dev[i][r] = de[row];
    }
  const f32x4 zero = {0.f, 0.f, 0.f, 0.f};
#pragma unroll
  for (int i = 0; i < 4; ++i)
#pragma unroll
    for (int j = 0; j < 4; ++j) {
      f32x4 L = __builtin_amdgcn_mfma_f32_16x16x32_bf16(ha[i], bb[j], zero, 0, 0, 0);
#pragma unroll
      for (int r = 0; r < 4; ++r) {
        const int row = m0 + wm + i * 16 + lrow * 4 + r;
        const int col = n0 + wn + j * 16 + lcol;
        const float v = scv[j] * smv[i][r] * (float)acc[i][j][r] + zpv[j] * rsv[i][r]
                      + wsv[j] * dev[i][r] + L[r];
        const size_t idx = (size_t)row * N + col;
        if (MODE == 0) Cb[idx] = (bf16)v;
        else {
          const float g = (float)gate[idx];
          Cb[idx] = (bf16)((g / (1.f + __expf(-g))) * v);
        }
      }
    }
}
#undef STAGE_A8
#undef STAGE_B8

// -------- Flash attention: Cqk [4096][4096] (q|k), VtG [(b*16+h)*128+d][2048] --------
// R5/R7-validated form (best attn: ~143-155us within the 1121us total).
// Falsified alternatives: R6 defer-max+setprio bundle (200us), R8 QBLK=64
// occupancy (176us), R9 QBLK=64+prefetch (175us), R10 XCD-grouped decode
// (210us: FETCH 139->41MB but same-(b,h) blocks lockstep-hammering one L2
// serialized the staging path — locality != speed when latency-bound).
// This structure is the session's local optimum for attention.
__global__ __launch_bounds__(256) void attn_kernel(const bf16* __restrict__ Cqk,
                                                   const bf16* __restrict__ VtG,
                                                   bf16* __restrict__ obuf) {
  const int qt = blockIdx.x, h = blockIdx.y, b = blockIdx.z;
  const int tid = threadIdx.x, wave = tid >> 6, lane = tid & 63;
  const int lcol = lane & 15, lrow = lane >> 4;
  const int base_m = b * 2048 + qt * 128;
  __shared__ bf16 Ks[64 * 128];
  __shared__ bf16 Vt[128 * 64];
  __shared__ bf16 Ps[4][32 * 72];
  bf16* ps = Ps[wave];
  bf16x8 qf[2][4];
#pragma unroll
  for (int i = 0; i < 2; ++i)
#pragma unroll
    for (int dk = 0; dk < 4; ++dk)
      qf[i][dk] = *(const bf16x8*)(Cqk + (size_t)(base_m + wave * 32 + i * 16 + lcol) * 4096
                                   + h * 128 + dk * 32 + lrow * 8);
  f32x4 of[2][8] = {};
  float m_run[2][4], l_run[2][4];
#pragma unroll
  for (int i = 0; i < 2; ++i)
#pragma unroll
    for (int r = 0; r < 4; ++r) { m_run[i][r] = -1e30f; l_run[i][r] = 0.f; }
  const float SCL2 = 0.12751874972f;
  const int vswz = (lane & 7) ^ (lane >> 3);

  for (int kt = 0; kt < 2048; kt += 64) {
#pragma unroll
    for (int r4 = 0; r4 < 4; ++r4) {
      const int s_low = r4 * 4 + lrow;
      gl_lds16(Cqk + (size_t)(b * 2048 + kt + wave * 16 + s_low) * 4096 + 2048 + h * 128
                   + (lcol ^ s_low) * 8,
               Ks + (wave * 16 + r4 * 4) * 128);
    }
#pragma unroll
    for (int r8 = 0; r8 < 4; ++r8)
      gl_lds16(VtG + (size_t)((b * 16 + h) * 128 + wave * 32 + r8 * 8 + (lane >> 3)) * 2048
                   + kt + vswz * 8,
               Vt + (wave * 32 + r8 * 8) * 64);
    __syncthreads();

    f32x4 sacc[2][4] = {};
#pragma unroll
    for (int jb = 0; jb < 4; ++jb) {
      bf16x8 kf[4];
#pragma unroll
      for (int dk = 0; dk < 4; ++dk)
        kf[dk] = *(const bf16x8*)(Ks + (jb * 16 + lcol) * 128 + ((dk * 4 + lrow) ^ lcol) * 8);
#pragma unroll
      for (int i = 0; i < 2; ++i)
#pragma unroll
        for (int dk = 0; dk < 4; ++dk)
          sacc[i][jb] = __builtin_amdgcn_mfma_f32_16x16x32_bf16(qf[i][dk], kf[dk], sacc[i][jb], 0, 0, 0);
    }

#pragma unroll
    for (int i = 0; i < 2; ++i) {
      float z[4][4], mx[4];
#pragma unroll
      for (int jb = 0; jb < 4; ++jb)
#pragma unroll
        for (int r = 0; r < 4; ++r) z[jb][r] = sacc[i][jb][r] * SCL2;
#pragma unroll
      for (int r = 0; r < 4; ++r)
        mx[r] = fmaxf(fmaxf(z[0][r], z[1][r]), fmaxf(z[2][r], z[3][r]));
#pragma unroll
      for (int d = 1; d < 16; d <<= 1)
#pragma unroll
        for (int r = 0; r < 4; ++r) mx[r] = fmaxf(mx[r], __shfl_xor(mx[r], d));
#pragma unroll
      for (int r = 0; r < 4; ++r) {
        const float mn = fmaxf(m_run[i][r], mx[r]);
        const float alpha = __builtin_amdgcn_exp2f(m_run[i][r] - mn);
        m_run[i][r] = mn;
        float srow = 0.f;
#pragma unroll
        for (int jb = 0; jb < 4; ++jb) {
          const float p = __builtin_amdgcn_exp2f(z[jb][r] - mn);
          z[jb][r] = p; srow += p;
        }
        l_run[i][r] = l_run[i][r] * alpha + srow;
#pragma unroll
        for (int db = 0; db < 8; ++db) of[i][db][r] *= alpha;
      }
#pragma unroll
      for (int jb = 0; jb < 4; ++jb)
#pragma unroll
        for (int r = 0; r < 4; ++r)
          ps[(i * 16 + lrow * 4 + r) * 72 + jb * 16 + lcol] = (bf16)z[jb][r];
    }

#pragma unroll
    for (int ss = 0; ss < 2; ++ss) {
      bf16x8 a0 = *(const bf16x8*)(ps + (0 * 16 + lcol) * 72 + ss * 32 + lrow * 8);
      bf16x8 a1 = *(const bf16x8*)(ps + (1 * 16 + lcol) * 72 + ss * 32 + lrow * 8);
#pragma unroll
      for (int db = 0; db < 8; ++db) {
        bf16x8 vf = *(const bf16x8*)(Vt + (db * 16 + lcol) * 64 + ((ss * 4 + lrow) ^ (lcol & 7)) * 8);
        of[0][db] = __builtin_amdgcn_mfma_f32_16x16x32_bf16(a0, vf, of[0][db], 0, 0, 0);
        of[1][db] = __builtin_amdgcn_mfma_f32_16x16x32_bf16(a1, vf, of[1][db], 0, 0, 0);
      }
    }
    __syncthreads();
  }
#pragma unroll
  for (int i = 0; i < 2; ++i)
#pragma unroll
    for (int r = 0; r < 4; ++r) {
      float l = l_run[i][r];
#pragma unroll
      for (int d = 1; d < 16; d <<= 1) l += __shfl_xor(l, d);
      const float inv = 1.f / l;
      const size_t rb = (size_t)(base_m + wave * 32 + i * 16 + lrow * 4 + r) * 2048 + h * 128;
#pragma unroll
      for (int db = 0; db < 8; ++db)
        obuf[rb + db * 16 + lcol] = (bf16)(of[i][db][r] * inv);
    }
}

extern "C" void kernel_launch(void* const* d_in, const int* in_sizes, int n_in,
                              void* d_out, int out_size, void* d_ws, size_t ws_size,
                              hipStream_t stream) {
  (void)in_sizes; (void)n_in; (void)out_size; (void)ws_size;
  const int*   q_qw = (const int*)d_in[0];   const float* q_sc = (const float*)d_in[1];
  const float* q_zp = (const float*)d_in[2]; const float* q_A  = (const float*)d_in[3];
  const float* q_B  = (const float*)d_in[4];
  const int*   k_qw = (const int*)d_in[5];   const float* k_sc = (const float*)d_in[6];
  const float* k_zp = (const float*)d_in[7]; const float* k_A  = (const float*)d_in[8];
  const float* k_B  = (const float*)d_in[9];
  const int*   v_qw = (const int*)d_in[10];  const float* v_sc = (const float*)d_in[11];
  const float* v_zp = (const float*)d_in[12];const float* v_A  = (const float*)d_in[13];
  const float* v_B  = (const float*)d_in[14];
  const int*   o_qw = (const int*)d_in[15];  const float* o_sc = (const float*)d_in[16];
  const float* o_zp = (const float*)d_in[17];const float* o_A  = (const float*)d_in[18];
  const float* o_B  = (const float*)d_in[19];
  const int*   g_qw = (const int*)d_in[20];  const float* g_sc = (const float*)d_in[21];
  const float* g_zp = (const float*)d_in[22];const float* g_A  = (const float*)d_in[23];
  const float* g_B  = (const float*)d_in[24];
  const int*   u_qw = (const int*)d_in[25];  const float* u_sc = (const float*)d_in[26];
  const float* u_zp = (const float*)d_in[27];const float* u_A  = (const float*)d_in[28];
  const float* u_B  = (const float*)d_in[29];
  const int*   d_qw = (const int*)d_in[30];  const float* d_sc = (const float*)d_in[31];
  const float* d_zp = (const float*)d_in[32];const float* d_A  = (const float*)d_in[33];
  const float* d_B  = (const float*)d_in[34];
  const float* x    = (const float*)d_in[35];
  const float* ln1w = (const float*)d_in[36];const float* ln1b = (const float*)d_in[37];
  const float* ln2w = (const float*)d_in[38];const float* ln2b = (const float*)d_in[39];

  // workspace arena — peak 112 MiB.  x1 lives in d_out (fp32).
  char* ws = (char*)d_ws;
  bf16* W = (bf16*)ws;                                    // 32 MiB dequant scratch (qkv/o/d)
  char* Wg8 = ws;                                         // FFN phase: int8 g-weights
  char* Wu8 = ws + (size_t)8192 * 2048;                   //            int8 u-weights
  char* p2  = ws + (size_t)32 * 1024 * 1024;              // 16 MiB region
  bf16* h   = (bf16*)p2;                                  // LN1 out (dead after qkv GEMM)
  char*  qh  = p2;                                        // FFN phase: int8 LN2 out (8.39 MB)
  float* s_m = (float*)(p2 + 8 * 1024 * 1024);            // 16 KB
  float* rs  = (float*)(p2 + 8 * 1024 * 1024 + 16384);    // 16 KB
  float* de  = (float*)(p2 + 8 * 1024 * 1024 + 32768);    // 16 KB
  bf16*  hA  = (bf16*)(p2 + 8 * 1024 * 1024 + 49152);     // 256 KB
  bf16*  B2g = (bf16*)(p2 + 8 * 1024 * 1024 + 49152 + 262144);  // 512 KB
  bf16*  B2u = B2g + (size_t)8192 * 32;                   // 512 KB
  float* wsg = (float*)((char*)(B2u + (size_t)8192 * 32));      // 32 KB
  float* wsu = wsg + 8192;                                // 32 KB
  bf16* C = (bf16*)(ws + (size_t)48 * 1024 * 1024);       // 64 MiB
  bf16* Cqk = C;                                          // [4096][4096] q|k
  bf16* VtG = C + (size_t)4096 * 4096;                    // [2*16*128][2048]
  bf16* obuf = VtG + (size_t)2 * 16 * 128 * 2048;         // [4096][2048]
  float* x1  = (float*)d_out;
  float* out = (float*)d_out;

  // 1. h = LN1(x)
  ln_kernel<<<4096, 256, 0, stream>>>(x, ln1w, ln1b, h);
  // 2. dequant W_q|W_k|W_v (6144x2048), single merged launch
  dequant3_kernel<<<6144, 256, 0, stream>>>(q_qw, q_sc, q_zp, q_A, q_B,
                                            k_qw, k_sc, k_zp, k_A, k_B,
                                            v_qw, v_sc, v_zp, v_A, v_B, W);
  // 3. qkv GEMM: q|k -> Cqk, v -> VtG (transposed packed stores)
  gemm8_kernel<3><<<dim3(48, 16), 512, 0, stream>>>(h, W, Cqk, nullptr, nullptr, VtG, 4096, 6144, 2048, 4096);
  // 4. attention
  attn_kernel<<<dim3(16, 16, 2), 256, 0, stream>>>(Cqk, VtG, obuf);
  // 5-6. x1 = x + o @ W_o^T
  dequant_kernel<<<2048, 256, 0, stream>>>(o_qw, o_sc, o_zp, o_A, o_B, W, 2048, 2048);
  gemm8_kernel<1><<<dim3(16, 16), 512, 0, stream>>>(obuf, W, nullptr, x1, x, nullptr, 4096, 2048, 2048, 2048);
  // 7. LN2 + int8 quantize (h region dead; reuse for qh/s_m/rs/de/hA/B2/wsum)
  ln_q_kernel<<<4096, 256, 0, stream>>>(x1, ln2w, ln2b, qh, s_m, rs, de);
  // 8. FFN LoRA/weight prep (W bf16 region dead; reuse for int8 weights)
  hA_kernel<<<1024, 256, 0, stream>>>(qh, s_m, g_A, u_A, hA);
  pack_w_kernel<<<8192, 256, 0, stream>>>(g_qw, g_sc, Wg8, wsg);
  pack_w_kernel<<<8192, 256, 0, stream>>>(u_qw, u_sc, Wu8, wsu);
  pack_b2_kernel<<<1024, 256, 0, stream>>>(g_B, u_B, B2g, B2u);
  // 9. g = dequant-epilogue(qh @ Wg8^T) -> C
  gemm_i8_kernel<0><<<dim3(64, 16), 512, 0, stream>>>(qh, Wg8, s_m, rs, de, g_sc, g_zp, wsg, hA, B2g, C, nullptr, 4096, 8192, 2048);
  // 10. ff = silu(g) * (qh @ Wu8^T dequant), in-place over C
  gemm_i8_kernel<1><<<dim3(64, 16), 512, 0, stream>>>(qh, Wu8, s_m, rs, de, u_sc, u_zp, wsu, hA, B2u, C, C, 4096, 8192, 2048);
  // 11-12. out = x1 + ff @ W_d^T (bf16 path)
  dequant_kernel<<<8192, 256, 0, stream>>>(d_qw, d_sc, d_zp, d_A, d_B, W, 2048, 8192);
  gemm8_kernel<1><<<dim3(16, 16), 512, 0, stream>>>(C, W, nullptr, out, x1, nullptr, 4096, 2048, 8192, 2048);
}